// Round 12
// baseline (350.615 us; speedup 1.0000x reference)
//
#include <hip/hip_runtime.h>
#include <math.h>

// Problem constants (shapes fixed by the reference)
#define D 128
#define HH 128
#define CC 64
#define NLAYERS 3
#define LN_EPS 1e-5f

typedef __attribute__((ext_vector_type(8))) short bf16x8;
typedef __attribute__((ext_vector_type(4))) float f32x4;
typedef unsigned short u16;
typedef unsigned int u32;

// round-to-nearest-even fp32 -> bf16 bits
__device__ __forceinline__ u16 f2bf(float f) {
    u32 u = __float_as_uint(f);
    u32 r = u + 0x7FFFu + ((u >> 16) & 1u);
    return (u16)(r >> 16);
}
__device__ __forceinline__ float bf2f(u16 h) {
    return __uint_as_float(((u32)h) << 16);
}

// ---------------------------------------------------------------------------
// k_prep: fused setup — zero cnt + x->bf16 (into xcH cols 0:128) +
// tile Wg (3 layers, one segment) + tile W1 + tile W2 (hi/lo).
// Tiled layout: [kc][q][n][j], k = kc*32 + q*8 + j.
// ---------------------------------------------------------------------------
__global__ void k_prep(const float* __restrict__ x, u16* __restrict__ xh,
                       const float* __restrict__ Wg, u16* __restrict__ WgtH,
                       const float* __restrict__ W1, u16* __restrict__ W1tH,
                       const float* __restrict__ W2, u16* __restrict__ W2tH,
                       u16* __restrict__ W2tL,
                       int* __restrict__ cnt, int N)
{
    int i = blockIdx.x * blockDim.x + threadIdx.x;
    // seg 0: zero cnt
    if (i < N) { cnt[i] = 0; return; }
    i -= N;
    // seg 1: x -> bf16 hi
    int nx = N * D;
    if (i < nx) {
        int row = i >> 7, c = i & 127;
        xh[(size_t)row * 512 + c] = f2bf(x[i]);
        return;
    }
    i -= nx;
    // seg 2: Wg (3 stacked 128x128 matrices; layout linear in kc)
    if (i < NLAYERS * D * HH) {
        int k = i >> 7, n = i & 127;
        int kc = k >> 5, q = (k >> 3) & 3, j = k & 7;
        WgtH[(((kc * 4 + q) << 7) + n) * 8 + j] = f2bf(Wg[i]);
        return;
    }
    i -= NLAYERS * D * HH;
    // seg 3: W1 (512x128)
    if (i < (D + NLAYERS * HH) * HH) {
        int k = i >> 7, n = i & 127;
        int kc = k >> 5, q = (k >> 3) & 3, j = k & 7;
        W1tH[(((kc * 4 + q) << 7) + n) * 8 + j] = f2bf(W1[i]);
        return;
    }
    i -= (D + NLAYERS * HH) * HH;
    // seg 4: W2 (128x64), hi + lo (split-3 in mlp phase 2)
    if (i < HH * CC) {
        int k = i >> 6, n = i & 63;
        int kc = k >> 5, q = (k >> 3) & 3, j = k & 7;
        float v = W2[i];
        u16 h = f2bf(v);
        int o = (((kc * 4 + q) << 6) + n) * 8 + j;
        W2tH[o] = h;
        W2tL[o] = f2bf(v - bf2f(h));
    }
}

// ---------------------------------------------------------------------------
// CSR build: count -> scan_a -> scan_c (block-sum scan inlined) -> scatter
// ---------------------------------------------------------------------------

__global__ void k_count(const int* __restrict__ dst, int* __restrict__ cnt, int E) {
    int i = blockIdx.x * blockDim.x + threadIdx.x;
    if (i < E) atomicAdd(&cnt[dst[i]], 1);
}

__global__ void k_scan_a(const int* __restrict__ cnt, int* __restrict__ rowptr,
                         int* __restrict__ bsum, int N) {
    __shared__ int s[1024];
    int tid = threadIdx.x;
    int i = blockIdx.x * 1024 + tid;
    int v = (i < N) ? cnt[i] : 0;
    s[tid] = v;
    __syncthreads();
    for (int off = 1; off < 1024; off <<= 1) {
        int t = (tid >= off) ? s[tid - off] : 0;
        __syncthreads();
        s[tid] += t;
        __syncthreads();
    }
    if (i < N) rowptr[i] = s[tid] - v;
    if (tid == 1023) bsum[blockIdx.x] = s[tid];
}

// finalize: each block re-scans the <=64 block sums (first wave), then applies;
// also computes dinv.
__global__ void k_scan_c(int* __restrict__ rowptr, const int* __restrict__ bsum,
                         const int* __restrict__ cnt, float* __restrict__ dinv,
                         int* __restrict__ cursor, int N, int E, int nsb) {
    __shared__ int sb[64];
    if (threadIdx.x < 64) {
        int t = threadIdx.x;
        int v = (t < nsb) ? bsum[t] : 0;
        int incl = v;
        #pragma unroll
        for (int off = 1; off < 64; off <<= 1) {
            int u = __shfl_up(incl, off, 64);
            if (t >= off) incl += u;
        }
        sb[t] = incl - v;   // exclusive
    }
    __syncthreads();
    int i = blockIdx.x * blockDim.x + threadIdx.x;
    if (i < N) {
        int v = rowptr[i] + sb[i >> 10];
        rowptr[i] = v;
        cursor[i] = v;
        dinv[i] = rsqrtf(1.0f + (float)cnt[i]);
    }
    if (i == 0) rowptr[N] = E;
}

// Scatter edges into CSR; pack src index + precomputed coef (dinv_s * dinv_d)
__global__ void k_scatter(const int* __restrict__ src, const int* __restrict__ dst,
                          const float* __restrict__ dinv,
                          int* __restrict__ cursor, int2* __restrict__ ecol, int E) {
    int i = blockIdx.x * blockDim.x + threadIdx.x;
    if (i < E) {
        int s = src[i], d = dst[i];
        int p = atomicAdd(&cursor[d], 1);
        float c = dinv[s] * dinv[d];
        ecol[p] = make_int2(s, __float_as_int(c));
    }
}

// ---------------------------------------------------------------------------
// Layer GEMM, K=128 (4 chunks): hWb = bf16(A @ W). LDS-free; all fragment
// loads issued up front, then MFMAs. A = bf16 slice of xcH (hi only).
// Block 64 rows x 128 cols; wave tile 32x64.
// ---------------------------------------------------------------------------
__global__ __launch_bounds__(256) void k_gemm_lf(
    const u16* __restrict__ A, int colOff,
    const u16* __restrict__ Bt, u16* __restrict__ OUTb, int N)
{
    const int tid  = threadIdx.x;
    const int lane = tid & 63;
    const int wave = tid >> 6;
    const int wr   = wave & 1;
    const int wc   = wave >> 1;
    const int quad = lane >> 4;
    const int l15  = lane & 15;
    const int row0 = blockIdx.x * 64;

    const u16* pA[2];
    #pragma unroll
    for (int i = 0; i < 2; ++i) {
        int r = row0 + wr * 32 + i * 16 + l15;
        if (r >= N) r = N - 1;
        pA[i] = A + (size_t)r * 512 + colOff + quad * 8;
    }
    const u16* pB = Bt + ((size_t)quad * 128 + wc * 64 + l15) * 8;

    bf16x8 ah[4][2], bh[4][4];
    #pragma unroll
    for (int kc = 0; kc < 4; ++kc) {
        #pragma unroll
        for (int i = 0; i < 2; ++i)
            ah[kc][i] = *(const bf16x8*)(pA[i] + kc * 32);
        #pragma unroll
        for (int j = 0; j < 4; ++j)
            bh[kc][j] = *(const bf16x8*)(pB + (size_t)kc * 4096 + j * 128);
    }

    f32x4 acc[2][4];
    #pragma unroll
    for (int i = 0; i < 2; ++i)
        #pragma unroll
        for (int j = 0; j < 4; ++j)
            #pragma unroll
            for (int r = 0; r < 4; ++r) acc[i][j][r] = 0.f;

    #pragma unroll
    for (int kc = 0; kc < 4; ++kc)
        #pragma unroll
        for (int i = 0; i < 2; ++i)
            #pragma unroll
            for (int j = 0; j < 4; ++j)
                acc[i][j] = __builtin_amdgcn_mfma_f32_16x16x32_bf16(ah[kc][i], bh[kc][j], acc[i][j], 0, 0, 0);

    #pragma unroll
    for (int i = 0; i < 2; ++i)
        #pragma unroll
        for (int j = 0; j < 4; ++j) {
            int col = wc * 64 + j * 16 + l15;
            #pragma unroll
            for (int r = 0; r < 4; ++r) {
                int grow = row0 + wr * 32 + i * 16 + quad * 4 + r;
                if (grow < N)
                    OUTb[(size_t)grow * 128 + col] = f2bf(acc[i][j][r]);
            }
        }
}

// ---------------------------------------------------------------------------
// Fused MLP (K-split): 32-row blocks, 4 waves. Wave w: col half wc = w&1,
// K-group kg = w>>1; 8 chunks each, 8 MFMA/chunk, 3-buffer pipeline.
// kg=1 partials via padded LDS; bias+relu+split -> sZ; softmax on waves 0-1.
// ---------------------------------------------------------------------------
__global__ __launch_bounds__(256) void k_mlp_fused(
    const u16* __restrict__ xcH,
    const u16* __restrict__ B1t, const float* __restrict__ b1,
    const u16* __restrict__ W2h, const u16* __restrict__ W2l,
    const float* __restrict__ b2, float* __restrict__ out, int N)
{
    __shared__ float sAcc[32 * 132];   // K-split partial sums (padded stride)
    __shared__ u16 sZh[32 * 128];      // [(qq*32 + r)*8 + j], z1 col = qq*8+j
    __shared__ u16 sZl[32 * 128];

    const int tid  = threadIdx.x;
    const int lane = tid & 63;
    const int wave = tid >> 6;
    const int wc   = wave & 1;   // 64-col half
    const int kg   = wave >> 1;  // K-group
    const int quad = lane >> 4;
    const int l15  = lane & 15;
    const int row0 = blockIdx.x * 32;

    const u16* pA[2];
    #pragma unroll
    for (int f = 0; f < 2; ++f) {
        int r = row0 + f * 16 + l15;
        if (r >= N) r = N - 1;
        pA[f] = xcH + (size_t)r * 512 + quad * 8;
    }
    const u16* pB = B1t + ((size_t)quad * 128 + wc * 64 + l15) * 8;

    f32x4 acc[2][4];
    #pragma unroll
    for (int f = 0; f < 2; ++f)
        #pragma unroll
        for (int j = 0; j < 4; ++j)
            #pragma unroll
            for (int r = 0; r < 4; ++r) acc[f][j][r] = 0.f;

    bf16x8 abuf[3][2], bbuf[3][4];
    #define LOADI(t, s)                                                          \
        {                                                                        \
            const int g = kg * 8 + (t);                                          \
            _Pragma("unroll")                                                    \
            for (int f = 0; f < 2; ++f)                                          \
                abuf[s][f] = *(const bf16x8*)(pA[f] + g * 32);                   \
            _Pragma("unroll")                                                    \
            for (int j = 0; j < 4; ++j)                                          \
                bbuf[s][j] = *(const bf16x8*)(pB + (size_t)g * 4096 + j * 128);  \
        }
    LOADI(0, 0)
    LOADI(1, 1)
    #pragma unroll
    for (int t = 0; t < 8; ++t) {
        if (t + 2 < 8) {
            const int s = (t + 2) % 3;
            LOADI(t + 2, s)
        }
        const int u = t % 3;
        #pragma unroll
        for (int f = 0; f < 2; ++f)
            #pragma unroll
            for (int j = 0; j < 4; ++j)
                acc[f][j] = __builtin_amdgcn_mfma_f32_16x16x32_bf16(abuf[u][f], bbuf[u][j], acc[f][j], 0, 0, 0);
    }
    #undef LOADI

    if (kg == 1) {
        #pragma unroll
        for (int f = 0; f < 2; ++f)
            #pragma unroll
            for (int jt = 0; jt < 4; ++jt) {
                int col = wc * 64 + jt * 16 + l15;
                #pragma unroll
                for (int r = 0; r < 4; ++r) {
                    int row = f * 16 + quad * 4 + r;
                    sAcc[row * 132 + col] = acc[f][jt][r];
                }
            }
    }
    __syncthreads();
    if (kg == 0) {
        #pragma unroll
        for (int jt = 0; jt < 4; ++jt) {
            int col = wc * 64 + jt * 16 + l15;
            float bv = b1[col];
            int qq = col >> 3, jj = col & 7;
            #pragma unroll
            for (int f = 0; f < 2; ++f) {
                #pragma unroll
                for (int rr = 0; rr < 4; ++rr) {
                    int row = f * 16 + quad * 4 + rr;
                    float v = fmaxf(acc[f][jt][rr] + sAcc[row * 132 + col] + bv, 0.f);
                    u16 h = f2bf(v);
                    sZh[(qq * 32 + row) * 8 + jj] = h;
                    sZl[(qq * 32 + row) * 8 + jj] = f2bf(v - bf2f(h));
                }
            }
        }
    }
    __syncthreads();

    if (kg == 0) {
        f32x4 oacc[4];
        #pragma unroll
        for (int j = 0; j < 4; ++j)
            #pragma unroll
            for (int r = 0; r < 4; ++r) oacc[j][r] = 0.f;

        #pragma unroll
        for (int kc = 0; kc < 4; ++kc) {
            int qq = kc * 4 + quad;
            bf16x8 zh = *(const bf16x8*)&sZh[(qq * 32 + wc * 16 + l15) * 8];
            bf16x8 zl = *(const bf16x8*)&sZl[(qq * 32 + wc * 16 + l15) * 8];
            #pragma unroll
            for (int jt = 0; jt < 4; ++jt) {
                int n = jt * 16 + l15;
                bf16x8 wh = *(const bf16x8*)&W2h[(qq * 64 + n) * 8];
                bf16x8 wl = *(const bf16x8*)&W2l[(qq * 64 + n) * 8];
                oacc[jt] = __builtin_amdgcn_mfma_f32_16x16x32_bf16(zh, wh, oacc[jt], 0, 0, 0);
                oacc[jt] = __builtin_amdgcn_mfma_f32_16x16x32_bf16(zh, wl, oacc[jt], 0, 0, 0);
                oacc[jt] = __builtin_amdgcn_mfma_f32_16x16x32_bf16(zl, wh, oacc[jt], 0, 0, 0);
            }
        }

        #pragma unroll
        for (int jt = 0; jt < 4; ++jt) {
            float bv = b2[jt * 16 + l15];
            #pragma unroll
            for (int r = 0; r < 4; ++r) oacc[jt][r] += bv;
        }
        #pragma unroll
        for (int r = 0; r < 4; ++r) {
            float m = fmaxf(fmaxf(oacc[0][r], oacc[1][r]), fmaxf(oacc[2][r], oacc[3][r]));
            #pragma unroll
            for (int mask = 8; mask; mask >>= 1) m = fmaxf(m, __shfl_xor(m, mask, 64));
            float p0 = __expf(oacc[0][r] - m);
            float p1 = __expf(oacc[1][r] - m);
            float p2 = __expf(oacc[2][r] - m);
            float p3 = __expf(oacc[3][r] - m);
            float s = p0 + p1 + p2 + p3;
            #pragma unroll
            for (int mask = 8; mask; mask >>= 1) s += __shfl_xor(s, mask, 64);
            float inv = 1.0f / s;
            int grow = row0 + wc * 16 + quad * 4 + r;
            if (grow < N) {
                float* o = out + (size_t)grow * CC + l15;
                o[0]  = p0 * inv;
                o[16] = p1 * inv;
                o[32] = p2 * inv;
                o[48] = p3 * inv;
            }
        }
    }
}

// ---------------------------------------------------------------------------
// Aggregation helpers: drain a node's remaining edges (batch 8 / 4 / 1)
// into two accumulator banks.
// ---------------------------------------------------------------------------
__device__ __forceinline__ void agg_drain(
    const u16* __restrict__ hWb, const int2* __restrict__ ecol, int f0,
    int& p, int q, float& ax, float& ay, float& bx, float& by)
{
    for (; p + 8 <= q; p += 8) {
        int2 e[8]; u32 v[8];
        #pragma unroll
        for (int t = 0; t < 8; ++t) e[t] = ecol[p + t];
        #pragma unroll
        for (int t = 0; t < 8; ++t)
            v[t] = *(const u32*)(hWb + (size_t)e[t].x * HH + f0);
        #pragma unroll
        for (int t = 0; t < 8; ++t) {
            float c = __int_as_float(e[t].y);
            float vx = bf2f((u16)v[t]) * c;
            float vy = bf2f((u16)(v[t] >> 16)) * c;
            if (t & 1) { bx += vx; by += vy; } else { ax += vx; ay += vy; }
        }
    }
    for (; p + 4 <= q; p += 4) {
        int2 e[4]; u32 v[4];
        #pragma unroll
        for (int t = 0; t < 4; ++t) e[t] = ecol[p + t];
        #pragma unroll
        for (int t = 0; t < 4; ++t)
            v[t] = *(const u32*)(hWb + (size_t)e[t].x * HH + f0);
        #pragma unroll
        for (int t = 0; t < 4; ++t) {
            float c = __int_as_float(e[t].y);
            float vx = bf2f((u16)v[t]) * c;
            float vy = bf2f((u16)(v[t] >> 16)) * c;
            if (t & 1) { bx += vx; by += vy; } else { ax += vx; ay += vy; }
        }
    }
    for (; p < q; ++p) {
        int2 e = ecol[p];
        u32 v = *(const u32*)(hWb + (size_t)e.x * HH + f0);
        float c = __int_as_float(e.y);
        ax += bf2f((u16)v) * c;
        ay += bf2f((u16)(v >> 16)) * c;
    }
}

// ---------------------------------------------------------------------------
// Aggregation (symmetric-normalized, self-loop) + bias + LayerNorm + ReLU.
// v3: TWO nodes per wave (independent gather chains interleaved 4+4 in the
// joint loop -> up to 16 outstanding loads) for memory-level parallelism.
// Grid-stride pairing (n, n+nwaves) keeps trip counts uniform.
// ---------------------------------------------------------------------------
__global__ __launch_bounds__(256, 6) void k_agg_ln(
    const u16* __restrict__ hWb,
    const int* __restrict__ rowptr, const int2* __restrict__ ecol,
    const float* __restrict__ dinv,
    const float* __restrict__ bg, const float* __restrict__ g,
    const float* __restrict__ b,
    u16* __restrict__ outHi, int N)
{
    const int lane = threadIdx.x & 63;
    const int f0 = lane * 2;

    const float bgx = bg[f0], bgy = bg[f0 + 1];
    const float gx  = g[f0],  gy  = g[f0 + 1];
    const float bx  = b[f0],  by  = b[f0 + 1];

    const int nw = gridDim.x * 4;
    for (int n0 = blockIdx.x * 4 + (threadIdx.x >> 6); n0 < N; n0 += 2 * nw) {
        const int n1 = n0 + nw;
        const bool has1 = (n1 < N);
        const int n1c = has1 ? n1 : n0;

        float di0 = dinv[n0];
        float di1 = dinv[n1c];

        u32 h0 = *(const u32*)(hWb + (size_t)n0 * HH + f0);
        u32 h1 = *(const u32*)(hWb + (size_t)n1c * HH + f0);

        float sc0 = di0 * di0, sc1 = di1 * di1;
        float a0x = bf2f((u16)h0) * sc0,        a0y = bf2f((u16)(h0 >> 16)) * sc0;
        float a1x = bf2f((u16)h1) * sc1,        a1y = bf2f((u16)(h1 >> 16)) * sc1;
        float b0x = 0.f, b0y = 0.f, b1x = 0.f, b1y = 0.f;

        int p0 = rowptr[n0],  q0 = rowptr[n0 + 1];
        int p1 = rowptr[n1c], q1 = rowptr[n1c + 1];
        if (!has1) p1 = q1;

        // joint loop: 4 edges per node per iteration, 8 gathers in flight
        for (; p0 + 4 <= q0 && p1 + 4 <= q1; p0 += 4, p1 += 4) {
            int2 ea[4], eb[4]; u32 va[4], vb[4];
            #pragma unroll
            for (int t = 0; t < 4; ++t) { ea[t] = ecol[p0 + t]; eb[t] = ecol[p1 + t]; }
            #pragma unroll
            for (int t = 0; t < 4; ++t) {
                va[t] = *(const u32*)(hWb + (size_t)ea[t].x * HH + f0);
                vb[t] = *(const u32*)(hWb + (size_t)eb[t].x * HH + f0);
            }
            #pragma unroll
            for (int t = 0; t < 4; ++t) {
                float ca = __int_as_float(ea[t].y);
                float cb = __int_as_float(eb[t].y);
                float vax = bf2f((u16)va[t]) * ca, vay = bf2f((u16)(va[t] >> 16)) * ca;
                float vbx = bf2f((u16)vb[t]) * cb, vby = bf2f((u16)(vb[t] >> 16)) * cb;
                if (t & 1) { b0x += vax; b0y += vay; b1x += vbx; b1y += vby; }
                else       { a0x += vax; a0y += vay; a1x += vbx; a1y += vby; }
            }
        }
        agg_drain(hWb, ecol, f0, p0, q0, a0x, a0y, b0x, b0y);
        agg_drain(hWb, ecol, f0, p1, q1, a1x, a1y, b1x, b1y);

        // node 0: LN + store
        {
            float ax = a0x + b0x + bgx;
            float ay = a0y + b0y + bgy;
            float ssum = ax + ay;
            #pragma unroll
            for (int off = 32; off; off >>= 1) ssum += __shfl_xor(ssum, off, 64);
            float mu = ssum * (1.0f / 128.0f);
            float dx = ax - mu, dy = ay - mu;
            float vsum = dx * dx + dy * dy;
            #pragma unroll
            for (int off = 32; off; off >>= 1) vsum += __shfl_xor(vsum, off, 64);
            float rstd = rsqrtf(vsum * (1.0f / 128.0f) + LN_EPS);
            float ox = fmaxf(gx * dx * rstd + bx, 0.f);
            float oy = fmaxf(gy * dy * rstd + by, 0.f);
            *(u32*)&outHi[(size_t)n0 * 512 + f0] = (u32)f2bf(ox) | ((u32)f2bf(oy) << 16);
        }
        // node 1: LN + store
        if (has1) {
            float ax = a1x + b1x + bgx;
            float ay = a1y + b1y + bgy;
            float ssum = ax + ay;
            #pragma unroll
            for (int off = 32; off; off >>= 1) ssum += __shfl_xor(ssum, off, 64);
            float mu = ssum * (1.0f / 128.0f);
            float dx = ax - mu, dy = ay - mu;
            float vsum = dx * dx + dy * dy;
            #pragma unroll
            for (int off = 32; off; off >>= 1) vsum += __shfl_xor(vsum, off, 64);
            float rstd = rsqrtf(vsum * (1.0f / 128.0f) + LN_EPS);
            float ox = fmaxf(gx * dx * rstd + bx, 0.f);
            float oy = fmaxf(gy * dy * rstd + by, 0.f);
            *(u32*)&outHi[(size_t)n1 * 512 + f0] = (u32)f2bf(ox) | ((u32)f2bf(oy) << 16);
        }
    }
}

// ---------------------------------------------------------------------------
// Host launcher
// ---------------------------------------------------------------------------
extern "C" void kernel_launch(void* const* d_in, const int* in_sizes, int n_in,
                              void* d_out, int out_size, void* d_ws, size_t ws_size,
                              hipStream_t stream) {
    const float* x   = (const float*)d_in[0];
    const int*   ei  = (const int*)  d_in[1];
    const float* Wg  = (const float*)d_in[2];
    const float* bg  = (const float*)d_in[3];
    const float* lng = (const float*)d_in[4];
    const float* lnb = (const float*)d_in[5];
    const float* W1  = (const float*)d_in[6];
    const float* b1  = (const float*)d_in[7];
    const float* W2  = (const float*)d_in[8];
    const float* b2  = (const float*)d_in[9];
    float* out = (float*)d_out;

    const int N = in_sizes[0] / D;
    const int E = in_sizes[1] / 2;
    const int* srcp = ei;
    const int* dstp = ei + E;

    char* ws = (char*)d_ws;
    size_t off = 0;
    auto alloc = [&](size_t bytes) -> void* {
        void* p = ws + off;
        off += (bytes + 511) & ~(size_t)511;
        return p;
    };
    int*   cnt    = (int*)  alloc((size_t)N * 4);
    int*   rowptr = (int*)  alloc((size_t)(N + 1) * 4);
    int*   cursor = (int*)  alloc((size_t)N * 4);
    int*   bsum   = (int*)  alloc(64 * 4);
    int2*  ecol   = (int2*) alloc((size_t)E * 8);
    float* dinv   = (float*)alloc((size_t)N * 4);
    u16*   hWb    = (u16*)  alloc((size_t)N * HH * 2);       // layer GEMM bf16 out
    u16*   xcH    = (u16*)  alloc((size_t)N * 512 * 2);      // [x|f1|f2|f3] bf16
    u16*   WgtH   = (u16*)  alloc((size_t)NLAYERS * D * HH * 2);
    u16*   W1tH   = (u16*)  alloc((size_t)(D + NLAYERS * HH) * HH * 2);
    u16*   W2tH   = (u16*)  alloc((size_t)HH * CC * 2);
    u16*   W2tL   = (u16*)  alloc((size_t)HH * CC * 2);

    const int B = 256;
    const int gE = (E + B - 1) / B;
    const int nsb = (N + 1023) / 1024;

    // fused prep: zero cnt + x->bf16 + all weight tilings (one launch)
    const int prepTotal = N + N * D + NLAYERS * D * HH
                        + (D + NLAYERS * HH) * HH + HH * CC;
    k_prep<<<(prepTotal + B - 1) / B, B, 0, stream>>>(x, xcH, Wg, WgtH, W1, W1tH,
                                                      W2, W2tH, W2tL, cnt, N);
    k_count<<<gE, B, 0, stream>>>(dstp, cnt, E);
    k_scan_a<<<nsb, 1024, 0, stream>>>(cnt, rowptr, bsum, N);
    k_scan_c<<<(N + B - 1) / B, B, 0, stream>>>(rowptr, bsum, cnt, dinv, cursor, N, E, nsb);
    k_scatter<<<gE, B, 0, stream>>>(srcp, dstp, dinv, cursor, ecol, E);

    const int gemmBlocks = (N + 63) / 64;
    const int mlpBlocks  = (N + 31) / 32;
    const int aggBlocks  = 2048;

    for (int l = 0; l < NLAYERS; ++l) {
        // hWb = bf16(h @ Wg[l])  (bias added after aggregation)
        k_gemm_lf<<<gemmBlocks, B, 0, stream>>>(xcH, l * HH,
                                                WgtH + (size_t)l * D * HH, hWb, N);
        k_agg_ln<<<aggBlocks, B, 0, stream>>>(hWb, rowptr, ecol, dinv,
                                              bg + (size_t)l * HH,
                                              lng + (size_t)l * HH,
                                              lnb + (size_t)l * HH,
                                              xcH + (size_t)(l + 1) * HH, N);
    }

    // out = softmax(relu([x|f1|f2|f3] @ W1 + b1) @ W2 + b2), fused, K-split
    k_mlp_fused<<<mlpBlocks, B, 0, stream>>>(xcH, W1tH, b1,
                                             W2tH, W2tL, b2, out, N);
}